// Round 1
// baseline (442.076 us; speedup 1.0000x reference)
//
#include <hip/hip_runtime.h>
#include <math.h>

// EMA scan: y[b,0,:] = x[b,0,:]; y[b,t,:] = a*x[b,t,:] + (1-a)*y[b,t-1,:]
// a = sigmoid(raw), per-channel.
//
// Layout: x, y are (B=16, T=4096, C=1024) fp32, C contiguous.
// Strategy: one block per (b, 64-channel group) = 16 x 16 = 256 blocks (1/CU),
// 1024 threads = 16 waves. T processed in 16 tiles of 256 timesteps; within a
// tile, wave w handles timesteps [w*16, w*16+16) for its 64 channels.
// Linear-recurrence composition: local scan with zero init -> publish per-wave
// carry to LDS -> all threads compose carries with per-channel d^16 -> fixup.

#define T_DIM 4096
#define C_DIM 1024
#define CG    64            // channels per block (== wavefront size)
#define NWAVE 16            // t-subchunks per tile (== waves per block)
#define LSUB  16            // timesteps per thread per tile
#define TILE_T (NWAVE * LSUB)     // 256
#define NTILES (T_DIM / TILE_T)   // 16

__global__ __launch_bounds__(1024, 1)
void ema_scan_kernel(const float* __restrict__ x,
                     const float* __restrict__ raw,
                     float* __restrict__ y) {
    __shared__ float carry_lds[NWAVE][CG];

    const int lane = threadIdx.x & (CG - 1);
    const int w    = threadIdx.x >> 6;
    const int cg   = blockIdx.x;          // channel group [0,16)
    const int b    = blockIdx.y;          // batch [0,16)
    const int c    = cg * CG + lane;

    // per-channel coefficients
    const float rv = raw[c];
    const float a  = 1.0f / (1.0f + expf(-rv));
    const float d  = 1.0f - a;
    const float d2 = d * d, d4 = d2 * d2, d8 = d4 * d4;
    const float d16 = d8 * d8;            // decay across one 16-step subchunk

    const size_t base = ((size_t)b * T_DIM) * (size_t)C_DIM + (size_t)c;

    float run = 0.0f;                     // exact y value at end of prev tile

    for (int tile = 0; tile < NTILES; ++tile) {
        const int t0 = tile * TILE_T + w * LSUB;
        const float* xp = x + base + (size_t)t0 * C_DIM;

        // 1) load 16 timesteps (independent, coalesced 256B per wave-load)
        float xv[LSUB];
        #pragma unroll
        for (int i = 0; i < LSUB; ++i) xv[i] = xp[(size_t)i * C_DIM];

        // 2) local scan with zero initial state
        float yl[LSUB];
        float s = 0.0f;
        if (tile == 0 && w == 0) {
            // global t = 0 special case: y_0 = x_0 exactly
            s = xv[0];
            yl[0] = s;
            #pragma unroll
            for (int i = 1; i < LSUB; ++i) { s = fmaf(a, xv[i], d * s); yl[i] = s; }
        } else {
            #pragma unroll
            for (int i = 0; i < LSUB; ++i) { s = fmaf(a, xv[i], d * s); yl[i] = s; }
        }

        // 3) publish per-wave local carry
        carry_lds[w][lane] = s;
        __syncthreads();

        // 4) compose: every thread walks all 16 subchunk carries for its channel
        //    carry_{j+1} = local_end_j + d^16 * carry_j
        float acc = run;
        float cin = 0.0f;                 // exclusive carry into my subchunk
        #pragma unroll
        for (int j = 0; j < NWAVE; ++j) {
            if (j == w) cin = acc;
            acc = fmaf(d16, acc, carry_lds[j][lane]);
        }
        run = acc;                        // exact carry into next tile
        __syncthreads();                  // protect LDS before next tile's writes

        // 5) fixup + store: y_t = y_local_t + d^(i+1) * carry_in
        float* yp = y + base + (size_t)t0 * C_DIM;
        float f = d;
        #pragma unroll
        for (int i = 0; i < LSUB; ++i) {
            yp[(size_t)i * C_DIM] = fmaf(f, cin, yl[i]);
            f *= d;
        }
    }
}

extern "C" void kernel_launch(void* const* d_in, const int* in_sizes, int n_in,
                              void* d_out, int out_size, void* d_ws, size_t ws_size,
                              hipStream_t stream) {
    const float* x   = (const float*)d_in[0];
    const float* raw = (const float*)d_in[1];
    float* y = (float*)d_out;

    dim3 grid(C_DIM / CG, 16);   // (16 channel-groups, 16 batches) = 256 blocks
    dim3 block(1024);
    ema_scan_kernel<<<grid, block, 0, stream>>>(x, raw, y);
}